// Round 11
// baseline (66.703 us; speedup 1.0000x reference)
//
#include <hip/hip_runtime.h>
#include <hip/hip_bf16.h>

// ---------------------------------------------------------------------------
// CNN: 4 images per 512-thread block (r7 per-thread structure, 2x images):
//  - activations column-parity deinterleaved in LDS (stride-2 conflict fix)
//  - conv1/conv2 weights via SCALAR loads (wave = oc-quad, readfirstlane)
//  - conv3 K-split partials through s_part LDS tree; 1024 items/512 thr
//  - weights NOT in LDS (r4); LDS ~52KB -> 3 blocks x 8 waves = 24 waves/CU
//    (r10: 2-image version ran at 16 waves/CU, 15% stall bubbles)
// ---------------------------------------------------------------------------
__global__ __launch_bounds__(512, 6) void cnn_kernel(
    const float* __restrict__ seq,
    const float* __restrict__ w1g, const float* __restrict__ b1g,
    const float* __restrict__ w2g, const float* __restrict__ b2g,
    const float* __restrict__ w3g, const float* __restrict__ b3g,
    const float* __restrict__ wdg, const float* __restrict__ bdg,
    float* __restrict__ out, int guard_off)
{
    const int tid = threadIdx.x;

    __shared__ __align__(16) float s_pool[4607];   // s_img(3360) / s_part(4607)
    __shared__ __align__(16) float s_a1[5824];     // [im*8+ch]*182 + par*91 + y*7 + xh
    __shared__ __align__(16) float s_a2[1920];     // [im*16+ch]*30 + par*15 + y*3 + xh
    __shared__ __align__(16) float s_p2[512];
    __shared__ __align__(16) float s_a3[128];
    __shared__ float s_logits[40];

    float* const s_img  = s_pool;   // [im]*840 + par*420 + row*15 + colHalf
    float* const s_part = s_pool;   // conv3 partials, pitch 9

    // ---- stage 4 images, deinterleaved by column parity (planes pitch 15) --
    {
        const float4* src = reinterpret_cast<const float4*>(seq + (size_t)blockIdx.x * 3136);
        for (int k = tid; k < 784; k += 512) {
            const float4 t = src[k];
            const int im = k / 196;
            const int r  = (k % 196) / 7;
            const int ch = (k % 7) * 2;
            float* pe = &s_img[im * 840 + r * 15 + ch];
            pe[0]   = t.x; pe[1]   = t.z;
            pe[420] = t.y; pe[421] = t.w;
        }
    }
    __syncthreads();

    // ================= conv1 (1->8) + relu + pool -> a1 =====================
    // wave = (im4, cq2); lane = position slot
    {
        const int wv = tid >> 6;
        const int im = __builtin_amdgcn_readfirstlane(wv >> 1);
        const int cq = __builtin_amdgcn_readfirstlane(wv & 1);
        const int slot = tid & 63;
        float w[4][9], bia[4];
        #pragma unroll
        for (int cc = 0; cc < 4; ++cc) {
            bia[cc] = b1g[cq * 4 + cc];                 // scalar (cq uniform)
            #pragma unroll
            for (int k = 0; k < 9; ++k) w[cc][k] = w1g[(cq * 4 + cc) * 9 + k];
        }
        for (int p = slot; p < 169; p += 64) {
            const int y = p / 13, x = p % 13;
            float win[4][4];
            #pragma unroll
            for (int r = 0; r < 4; ++r) {
                const float* pe = &s_img[im * 840 + (2 * y + r) * 15 + x];
                win[r][0] = pe[0];   win[r][2] = pe[1];
                win[r][1] = pe[420]; win[r][3] = pe[421];
            }
            #pragma unroll
            for (int cc = 0; cc < 4; ++cc) {
                float pool = 0.f;
                #pragma unroll
                for (int dy = 0; dy < 2; ++dy)
                #pragma unroll
                for (int dx = 0; dx < 2; ++dx) {
                    float s = bia[cc];
                    #pragma unroll
                    for (int ky = 0; ky < 3; ++ky)
                    #pragma unroll
                    for (int kx = 0; kx < 3; ++kx)
                        s = fmaf(win[dy + ky][dx + kx], w[cc][ky * 3 + kx], s);
                    pool += fmaxf(s, 0.f);
                }
                s_a1[(im * 8 + cq * 4 + cc) * 182 + (x & 1) * 91 + y * 7 + (x >> 1)]
                    = pool * 0.25f;
            }
        }
    }
    __syncthreads();   // also: s_img region dead after conv1

    // ================= conv2 (8->16) + relu + pool -> a2 ====================
    // wave = (q4, imh2) -> scalar weights; lane = (im-in-pair, pos)
    {
        const int wv   = tid >> 6;
        const int q    = __builtin_amdgcn_readfirstlane(wv >> 1);
        const int imh  = __builtin_amdgcn_readfirstlane(wv & 1);
        const int l    = tid & 63;
        const int im   = imh * 2 + (l >> 5), slot = l & 31;
        if (slot < 25) {
            const int y = slot / 5, x = slot % 5;
            float acc2[4][4];
            #pragma unroll
            for (int o = 0; o < 4; ++o)
                #pragma unroll
                for (int s = 0; s < 4; ++s) acc2[o][s] = 0.f;

            const float* wq = w2g + q * 288;            // ((q*4+o)*8+ci)*9
            for (int ci = 0; ci < 8; ++ci) {
                float win[4][4];
                #pragma unroll
                for (int r = 0; r < 4; ++r) {
                    const float* pe = &s_a1[(im * 8 + ci) * 182 + (2 * y + r) * 7 + x];
                    win[r][0] = pe[0];  win[r][2] = pe[1];
                    win[r][1] = pe[91]; win[r][3] = pe[92];
                }
                #pragma unroll
                for (int o = 0; o < 4; ++o) {
                    float w[9];
                    #pragma unroll
                    for (int k = 0; k < 9; ++k)
                        w[k] = wq[o * 72 + ci * 9 + k]; // uniform -> s_load
                    #pragma unroll
                    for (int dy = 0; dy < 2; ++dy)
                    #pragma unroll
                    for (int dx = 0; dx < 2; ++dx)
                        #pragma unroll
                        for (int ky = 0; ky < 3; ++ky)
                        #pragma unroll
                        for (int kx = 0; kx < 3; ++kx)
                            acc2[o][dy * 2 + dx] =
                                fmaf(win[dy + ky][dx + kx], w[ky * 3 + kx], acc2[o][dy * 2 + dx]);
                }
            }
            #pragma unroll
            for (int o = 0; o < 4; ++o) {
                const float b = b2g[q * 4 + o];         // scalar
                float pool = 0.f;
                #pragma unroll
                for (int s = 0; s < 4; ++s) pool += fmaxf(acc2[o][s] + b, 0.f);
                s_a2[(im * 16 + q * 4 + o) * 30 + (x & 1) * 15 + y * 3 + (x >> 1)]
                    = pool * 0.25f;
            }
        }
    }
    __syncthreads();

    // ====== conv3 (16->32) partials, K split over 8 groups, im-pair ========
    {
        const int oc = tid >> 4, cg = (tid >> 1) & 7, imh = tid & 1;
        float w[2][9];
        #pragma unroll
        for (int cc = 0; cc < 2; ++cc)
            #pragma unroll
            for (int k = 0; k < 9; ++k)
                w[cc][k] = w3g[(oc * 16 + 2 * cg + cc) * 9 + k];
        float pacc[2][4];
        #pragma unroll
        for (int i = 0; i < 2; ++i)
            #pragma unroll
            for (int s = 0; s < 4; ++s) pacc[i][s] = 0.f;

        #pragma unroll
        for (int cc = 0; cc < 2; ++cc) {
            const int ci = 2 * cg + cc;
            #pragma unroll
            for (int ii = 0; ii < 2; ++ii) {
                const int im = imh * 2 + ii;
                float win[4][4];
                #pragma unroll
                for (int r = 0; r < 4; ++r) {
                    const float* pe = &s_a2[(im * 16 + ci) * 30 + r * 3];
                    win[r][0] = pe[0];  win[r][2] = pe[1];
                    win[r][1] = pe[15]; win[r][3] = pe[16];
                }
                #pragma unroll
                for (int dy = 0; dy < 2; ++dy)
                #pragma unroll
                for (int dx = 0; dx < 2; ++dx)
                    #pragma unroll
                    for (int ky = 0; ky < 3; ++ky)
                    #pragma unroll
                    for (int kx = 0; kx < 3; ++kx)
                        pacc[ii][dy * 2 + dx] =
                            fmaf(win[dy + ky][dx + kx], w[cc][ky * 3 + kx], pacc[ii][dy * 2 + dx]);
            }
        }
        __syncthreads();   // s_pool: image region dead, partial region begins
        #pragma unroll
        for (int ii = 0; ii < 2; ++ii)
            #pragma unroll
            for (int s = 0; s < 4; ++s)
                s_part[((oc * 4 + s) * 4 + imh * 2 + ii) * 9 + cg] = pacc[ii][s];
    }
    __syncthreads();

    {
        // tid = oc*16 + sub*4 + im  <->  layout ((oc*4+sub)*4+im)*9
        const int oc = tid >> 4;
        const float* pp = &s_part[tid * 9];
        float sum = b3g[oc];
        #pragma unroll
        for (int k = 0; k < 8; ++k) sum += pp[k];
        const int sub = (tid >> 2) & 3, im = tid & 3;
        s_p2[im * 128 + oc * 4 + sub] = fmaxf(sum, 0.f);
    }
    __syncthreads();

    if (tid < 128) {
        const int im = tid >> 5, oc = tid & 31;
        const float4 t = *reinterpret_cast<const float4*>(&s_p2[im * 128 + oc * 4]);
        s_a3[im * 32 + oc] = 0.25f * (t.x + t.y + t.z + t.w);
    }
    __syncthreads();

    // ============ dense (32->10) + softmax, wave 0 only, wave-sync ==========
    if (tid < 64) {
        if (tid < 40) {
            const int im = tid / 10, j = tid - im * 10;
            float s = bdg[j];
            #pragma unroll
            for (int i = 0; i < 32; ++i) s = fmaf(s_a3[im * 32 + i], wdg[j * 32 + i], s);
            s_logits[tid] = s;
        }
        __builtin_amdgcn_wave_barrier();
        asm volatile("s_waitcnt lgkmcnt(0)" ::: "memory");
        if (tid < 40) {
            const int im = tid / 10, j = tid - im * 10;
            const float* lg = &s_logits[im * 10];
            float m = -1e30f;
            #pragma unroll
            for (int k = 0; k < 10; ++k) m = fmaxf(m, lg[k]);
            float sum = 0.f;
            #pragma unroll
            for (int k = 0; k < 10; ++k) sum += __expf(lg[k] - m);
            const float p = __expf(lg[j] - m) / sum;
            const size_t gi = (size_t)(blockIdx.x * 4 + im) * 10 + j;
            out[gi] = p;
            out[(size_t)guard_off + gi] = p;
        }
    }
}

// ---------------------------------------------------------------------------
// Chain: 8 wave-synchronous chunks of 8 steps per 512-thread block (128
// blocks). Wave 0 folds the block's 8 chunk matrices -> one partial per block.
// ---------------------------------------------------------------------------
#define CH_STEPS 8
#define CH_WAVES 8

__global__ __launch_bounds__(512) void chain_kernel(
    const float* __restrict__ guards,   // [T,10]
    const float* __restrict__ trans,    // [10,9,10]
    float* __restrict__ partials,       // [gridDim,10,10]
    int T)
{
    __shared__ __align__(16) float comp[1000];
    __shared__ __align__(16) float Pm[CH_WAVES][100];
    __shared__ __align__(16) float Em[CH_WAVES][100];
    __shared__ __align__(16) float Gm[CH_WAVES][CH_STEPS * 10];

    const int tid = threadIdx.x;
    const int w = tid >> 6, l = tid & 63;

    if (tid < 90) {
        const int g = tid / 9, i = tid % 9;
        const float* row = trans + (g * 9 + i) * 10;
        float v[10], m = -1e30f;
        #pragma unroll
        for (int j = 0; j < 10; ++j) { v[j] = row[j]; m = fmaxf(m, v[j]); }
        float e[10], sum = 0.f;
        #pragma unroll
        for (int j = 0; j < 10; ++j) { e[j] = __expf((v[j] - m) * 10.f); sum += e[j]; }
        const float inv = 1.f / sum;
        #pragma unroll
        for (int j = 0; j < 10; ++j) comp[g * 100 + i * 10 + j] = e[j] * inv;
    } else if (tid < 100) {
        const int g = tid - 90;
        #pragma unroll
        for (int j = 0; j < 10; ++j) comp[g * 100 + 90 + j] = (j == 9) ? 1.f : 0.f;
    }

    const int chunk = blockIdx.x * CH_WAVES + w;
    const int base  = chunk * CH_STEPS;
    const int nst   = min(CH_STEPS, T - base);

    if (l < 20 && base * 10 + l * 4 < T * 10) {
        const float4* gp = reinterpret_cast<const float4*>(guards + (size_t)base * 10);
        reinterpret_cast<float4*>(Gm[w])[l] = gp[l];
    }
    if (l < 50) {
        const int e0 = 2 * l, e1 = 2 * l + 1;
        Pm[w][e0] = (e0 / 10 == e0 % 10) ? 1.f : 0.f;
        Pm[w][e1] = (e1 / 10 == e1 % 10) ? 1.f : 0.f;
    }
    __syncthreads();

    const int e0 = 2 * l, i = e0 / 10, j = e0 % 10;
    if (l < 50) {
        for (int t = 0; t < nst; ++t) {
            float gv[10];
            #pragma unroll
            for (int g = 0; g < 10; ++g) gv[g] = Gm[w][t * 10 + g];
            float a = 0.f, b = 0.f;
            #pragma unroll
            for (int g = 0; g < 10; ++g) {
                const float2 c2 = *reinterpret_cast<const float2*>(&comp[g * 100 + e0]);
                a = fmaf(gv[g], c2.x, a);
                b = fmaf(gv[g], c2.y, b);
            }
            *reinterpret_cast<float2*>(&Em[w][e0]) = make_float2(a, b);
            __builtin_amdgcn_wave_barrier();
            asm volatile("s_waitcnt lgkmcnt(0)" ::: "memory");
            float s0 = 0.f, s1 = 0.f;
            #pragma unroll
            for (int k = 0; k < 10; ++k) {
                const float pk = Pm[w][i * 10 + k];
                const float2 ek = *reinterpret_cast<const float2*>(&Em[w][k * 10 + j]);
                s0 = fmaf(pk, ek.x, s0);
                s1 = fmaf(pk, ek.y, s1);
            }
            __builtin_amdgcn_wave_barrier();
            *reinterpret_cast<float2*>(&Pm[w][e0]) = make_float2(s0, s1);
            __builtin_amdgcn_wave_barrier();
        }
    }
    __syncthreads();

    if (w == 0 && l < 50) {
        float r0 = Pm[0][e0], r1 = Pm[0][e0 + 1];
        for (int q = 1; q < CH_WAVES; ++q) {
            *reinterpret_cast<float2*>(&Em[0][e0]) = make_float2(r0, r1);
            __builtin_amdgcn_wave_barrier();
            asm volatile("s_waitcnt lgkmcnt(0)" ::: "memory");
            float s0 = 0.f, s1 = 0.f;
            #pragma unroll
            for (int k = 0; k < 10; ++k) {
                const float rk = Em[0][i * 10 + k];
                const float2 pk2 = *reinterpret_cast<const float2*>(&Pm[q][k * 10 + j]);
                s0 = fmaf(rk, pk2.x, s0);
                s1 = fmaf(rk, pk2.y, s1);
            }
            r0 = s0; r1 = s1;
            __builtin_amdgcn_wave_barrier();
        }
        *reinterpret_cast<float2*>(&partials[(size_t)blockIdx.x * 100 + e0]) =
            make_float2(r0, r1);
    }
}

// ---------------------------------------------------------------------------
// Finalize (two-level): 8 waves each matrix-fold 16 partials in parallel,
// then wave 0 vector-folds the 8 wave results.
// ---------------------------------------------------------------------------
__global__ __launch_bounds__(512) void finalize_kernel(
    const float* __restrict__ partials, float* __restrict__ out_final, int nmat)
{
    __shared__ __align__(16) float sp[12800];      // 128 matrices, 51.2 KB
    __shared__ __align__(16) float Rt[8][100];
    __shared__ __align__(16) float Et[8][100];

    const int tid = threadIdx.x;
    const int w = tid >> 6, l = tid & 63;
    const int mpw = nmat / 8;                      // matrices per wave (16)

    for (int idx = tid; idx < nmat * 25; idx += 512)
        reinterpret_cast<float4*>(sp)[idx] = reinterpret_cast<const float4*>(partials)[idx];
    __syncthreads();

    const int e0 = 2 * l, i = e0 / 10, j = e0 % 10;
    if (l < 50) {
        const float* mybase = sp + (size_t)w * mpw * 100;
        float r0 = mybase[e0], r1 = mybase[e0 + 1];
        for (int q = 1; q < mpw; ++q) {
            *reinterpret_cast<float2*>(&Et[w][e0]) = make_float2(r0, r1);
            __builtin_amdgcn_wave_barrier();
            asm volatile("s_waitcnt lgkmcnt(0)" ::: "memory");
            float s0 = 0.f, s1 = 0.f;
            #pragma unroll
            for (int k = 0; k < 10; ++k) {
                const float rk = Et[w][i * 10 + k];
                const float2 pk2 = *reinterpret_cast<const float2*>(&mybase[q * 100 + k * 10 + j]);
                s0 = fmaf(rk, pk2.x, s0);
                s1 = fmaf(rk, pk2.y, s1);
            }
            r0 = s0; r1 = s1;
            __builtin_amdgcn_wave_barrier();
        }
        *reinterpret_cast<float2*>(&Rt[w][e0]) = make_float2(r0, r1);
    }
    __syncthreads();

    if (tid < 64) {                                // wave 0: vector fold of 8
        float s = (l == 0) ? 1.f : 0.f;
        for (int b = 0; b < 8; ++b) {
            float acc = 0.f;
            #pragma unroll
            for (int k = 0; k < 10; ++k) {
                const float pv = (l < 10) ? Rt[b][k * 10 + l] : 0.f;
                acc = fmaf(__shfl(s, k, 64), pv, acc);
            }
            s = acc;
        }
        if (l < 10) out_final[l] = s;
    }
}

extern "C" void kernel_launch(void* const* d_in, const int* in_sizes, int n_in,
                              void* d_out, int out_size, void* d_ws, size_t ws_size,
                              hipStream_t stream)
{
    const float* seq = (const float*)d_in[0];
    const float* w1  = (const float*)d_in[1];
    const float* b1  = (const float*)d_in[2];
    const float* w2  = (const float*)d_in[3];
    const float* b2  = (const float*)d_in[4];
    const float* w3  = (const float*)d_in[5];
    const float* b3  = (const float*)d_in[6];
    const float* wd  = (const float*)d_in[7];
    const float* bd  = (const float*)d_in[8];
    const float* tm  = (const float*)d_in[9];
    float* out = (float*)d_out;

    const int T = in_sizes[0] / 784;                       // 8192
    const int guard_off = T * 10;
    const int final_off = 2 * T * 10;
    const int nblk = (T + CH_WAVES * CH_STEPS - 1) / (CH_WAVES * CH_STEPS);  // 128

    float* partials = (float*)d_ws;                        // nblk*100 floats

    cnn_kernel<<<T / 4, 512, 0, stream>>>(seq, w1, b1, w2, b2, w3, b3, wd, bd,
                                          out, guard_off);
    chain_kernel<<<nblk, 512, 0, stream>>>(out, tm, partials, T);
    finalize_kernel<<<1, 512, 0, stream>>>(partials, out + final_off, nblk);
}

// Round 12
// 63.839 us; speedup vs baseline: 1.0449x; 1.0449x over previous
//
#include <hip/hip_runtime.h>
#include <hip/hip_bf16.h>

// ---------------------------------------------------------------------------
// CNN (round-10 structure, best measured 54.6us at VGPR=40):
//  - activations column-parity deinterleaved in LDS (stride-2 conflict fix)
//  - conv1/conv2 weights via SCALAR loads (wave = oc-quad, readfirstlane)
//  - conv3 K-split partials through s_part LDS tree
//  - weights NOT in LDS (r4); 2 images/block (r11: 4-image regressed)
//  - launch_bounds (256,4): A/B test vs (256,6)'s VGPR=40 cap — hypothesis:
//    ~1.7x hidden VALU overhead is register-pressure moves (r8: 40->32 = -6%)
// ---------------------------------------------------------------------------
__global__ __launch_bounds__(256, 4) void cnn_kernel(
    const float* __restrict__ seq,
    const float* __restrict__ w1g, const float* __restrict__ b1g,
    const float* __restrict__ w2g, const float* __restrict__ b2g,
    const float* __restrict__ w3g, const float* __restrict__ b3g,
    const float* __restrict__ wdg, const float* __restrict__ bdg,
    float* __restrict__ out, int guard_off)
{
    const int tid = threadIdx.x;

    __shared__ __align__(16) float s_pool[2303];   // s_img(1680) / s_part(2303)
    __shared__ __align__(16) float s_a1[2912];     // [im*8+ch]*182 + par*91 + y*7 + xh
    __shared__ __align__(16) float s_a2[960];      // [im*16+ch]*30 + par*15 + y*3 + xh
    __shared__ __align__(16) float s_p2[256];
    __shared__ __align__(16) float s_a3[64];
    __shared__ float s_logits[20];

    float* const s_img  = s_pool;   // [im]*840 + par*420 + row*15 + colHalf
    float* const s_part = s_pool;   // conv3 partials, pitch 9

    // ---- stage 2 images, deinterleaved by column parity (planes pitch 15) --
    {
        const float4* src = reinterpret_cast<const float4*>(seq + (size_t)blockIdx.x * 1568);
        for (int k = tid; k < 392; k += 256) {
            const float4 t = src[k];
            const int im = k / 196;
            const int r  = (k % 196) / 7;
            const int ch = (k % 7) * 2;
            float* pe = &s_img[im * 840 + r * 15 + ch];
            pe[0]   = t.x; pe[1]   = t.z;
            pe[420] = t.y; pe[421] = t.w;
        }
    }
    __syncthreads();

    // ================= conv1 (1->8) + relu + pool -> a1 =====================
    {
        const int im = __builtin_amdgcn_readfirstlane(tid >> 7);
        const int cq = __builtin_amdgcn_readfirstlane((tid >> 6) & 1);
        const int slot = tid & 63;
        float w[4][9], bia[4];
        #pragma unroll
        for (int cc = 0; cc < 4; ++cc) {
            bia[cc] = b1g[cq * 4 + cc];                 // scalar (cq uniform)
            #pragma unroll
            for (int k = 0; k < 9; ++k) w[cc][k] = w1g[(cq * 4 + cc) * 9 + k];
        }
        for (int p = slot; p < 169; p += 64) {
            const int y = p / 13, x = p % 13;
            float win[4][4];
            #pragma unroll
            for (int r = 0; r < 4; ++r) {
                const float* pe = &s_img[im * 840 + (2 * y + r) * 15 + x];
                win[r][0] = pe[0];   win[r][2] = pe[1];
                win[r][1] = pe[420]; win[r][3] = pe[421];
            }
            #pragma unroll
            for (int cc = 0; cc < 4; ++cc) {
                float pool = 0.f;
                #pragma unroll
                for (int dy = 0; dy < 2; ++dy)
                #pragma unroll
                for (int dx = 0; dx < 2; ++dx) {
                    float s = bia[cc];
                    #pragma unroll
                    for (int ky = 0; ky < 3; ++ky)
                    #pragma unroll
                    for (int kx = 0; kx < 3; ++kx)
                        s = fmaf(win[dy + ky][dx + kx], w[cc][ky * 3 + kx], s);
                    pool += fmaxf(s, 0.f);
                }
                s_a1[(im * 8 + cq * 4 + cc) * 182 + (x & 1) * 91 + y * 7 + (x >> 1)]
                    = pool * 0.25f;
            }
        }
    }
    __syncthreads();

    // ================= conv2 (8->16) + relu + pool -> a2 ====================
    // wave = oc-quad q (uniform -> scalar weights); lane = (im, pos)
    {
        const int q    = __builtin_amdgcn_readfirstlane(tid >> 6);
        const int l    = tid & 63;
        const int im   = l >> 5, slot = l & 31;
        if (slot < 25) {
            const int y = slot / 5, x = slot % 5;
            float acc2[4][4];
            #pragma unroll
            for (int o = 0; o < 4; ++o)
                #pragma unroll
                for (int s = 0; s < 4; ++s) acc2[o][s] = 0.f;

            const float* wq = w2g + q * 288;            // ((q*4+o)*8+ci)*9
            for (int ci = 0; ci < 8; ++ci) {
                float win[4][4];
                #pragma unroll
                for (int r = 0; r < 4; ++r) {
                    const float* pe = &s_a1[(im * 8 + ci) * 182 + (2 * y + r) * 7 + x];
                    win[r][0] = pe[0];  win[r][2] = pe[1];
                    win[r][1] = pe[91]; win[r][3] = pe[92];
                }
                #pragma unroll
                for (int o = 0; o < 4; ++o) {
                    float w[9];
                    #pragma unroll
                    for (int k = 0; k < 9; ++k)
                        w[k] = wq[o * 72 + ci * 9 + k]; // uniform -> s_load
                    #pragma unroll
                    for (int dy = 0; dy < 2; ++dy)
                    #pragma unroll
                    for (int dx = 0; dx < 2; ++dx)
                        #pragma unroll
                        for (int ky = 0; ky < 3; ++ky)
                        #pragma unroll
                        for (int kx = 0; kx < 3; ++kx)
                            acc2[o][dy * 2 + dx] =
                                fmaf(win[dy + ky][dx + kx], w[ky * 3 + kx], acc2[o][dy * 2 + dx]);
                }
            }
            #pragma unroll
            for (int o = 0; o < 4; ++o) {
                const float b = b2g[q * 4 + o];         // scalar
                float pool = 0.f;
                #pragma unroll
                for (int s = 0; s < 4; ++s) pool += fmaxf(acc2[o][s] + b, 0.f);
                s_a2[(im * 16 + q * 4 + o) * 30 + (x & 1) * 15 + y * 3 + (x >> 1)]
                    = pool * 0.25f;
            }
        }
    }
    __syncthreads();

    // ================= conv3 (16->32) partials, K split over 8 groups =======
    {
        const int oc = tid >> 3, cg = tid & 7;
        float w[2][9];
        #pragma unroll
        for (int cc = 0; cc < 2; ++cc)
            #pragma unroll
            for (int k = 0; k < 9; ++k)
                w[cc][k] = w3g[(oc * 16 + 2 * cg + cc) * 9 + k];
        float pacc[2][4];
        #pragma unroll
        for (int i = 0; i < 2; ++i)
            #pragma unroll
            for (int s = 0; s < 4; ++s) pacc[i][s] = 0.f;

        #pragma unroll
        for (int cc = 0; cc < 2; ++cc) {
            const int ci = 2 * cg + cc;
            #pragma unroll
            for (int im = 0; im < 2; ++im) {
                float win[4][4];
                #pragma unroll
                for (int r = 0; r < 4; ++r) {
                    const float* pe = &s_a2[(im * 16 + ci) * 30 + r * 3];
                    win[r][0] = pe[0];  win[r][2] = pe[1];
                    win[r][1] = pe[15]; win[r][3] = pe[16];
                }
                #pragma unroll
                for (int dy = 0; dy < 2; ++dy)
                #pragma unroll
                for (int dx = 0; dx < 2; ++dx)
                    #pragma unroll
                    for (int ky = 0; ky < 3; ++ky)
                    #pragma unroll
                    for (int kx = 0; kx < 3; ++kx)
                        pacc[im][dy * 2 + dx] =
                            fmaf(win[dy + ky][dx + kx], w[cc][ky * 3 + kx], pacc[im][dy * 2 + dx]);
            }
        }
        __syncthreads();   // s_pool: image region dead, partial region begins
        #pragma unroll
        for (int im = 0; im < 2; ++im)
            #pragma unroll
            for (int s = 0; s < 4; ++s)
                s_part[((oc * 4 + s) * 2 + im) * 9 + cg] = pacc[im][s];
    }
    __syncthreads();

    {
        const int oc = tid >> 3;
        const float* pp = &s_part[tid * 9];
        float sum = b3g[oc];
        #pragma unroll
        for (int k = 0; k < 8; ++k) sum += pp[k];
        const int sub = (tid >> 1) & 3, im = tid & 1;
        s_p2[im * 128 + oc * 4 + sub] = fmaxf(sum, 0.f);
    }
    __syncthreads();

    if (tid < 64) {
        const int im = tid >> 5, oc = tid & 31;
        const float4 t = *reinterpret_cast<const float4*>(&s_p2[im * 128 + oc * 4]);
        s_a3[im * 32 + oc] = 0.25f * (t.x + t.y + t.z + t.w);
    }
    __syncthreads();

    if (tid < 20) {
        const int im = (tid >= 10), j = tid - im * 10;
        float s = bdg[j];
        #pragma unroll
        for (int i = 0; i < 32; ++i) s = fmaf(s_a3[im * 32 + i], wdg[j * 32 + i], s);
        s_logits[im * 10 + j] = s;
    }
    __syncthreads();

    if (tid < 20) {
        const int im = (tid >= 10), j = tid - im * 10;
        const float* lg = &s_logits[im * 10];
        float m = -1e30f;
        #pragma unroll
        for (int k = 0; k < 10; ++k) m = fmaxf(m, lg[k]);
        float sum = 0.f;
        #pragma unroll
        for (int k = 0; k < 10; ++k) sum += __expf(lg[k] - m);
        const float p = __expf(lg[j] - m) / sum;
        const size_t gi = (size_t)(blockIdx.x * 2 + im) * 10 + j;
        out[gi] = p;
        out[(size_t)guard_off + gi] = p;
    }
}

// ---------------------------------------------------------------------------
// Chain: 8 wave-synchronous chunks of 8 steps per 512-thread block (128
// blocks). Wave 0 folds the block's 8 chunk matrices -> one partial per block.
// ---------------------------------------------------------------------------
#define CH_STEPS 8
#define CH_WAVES 8

__global__ __launch_bounds__(512) void chain_kernel(
    const float* __restrict__ guards,   // [T,10]
    const float* __restrict__ trans,    // [10,9,10]
    float* __restrict__ partials,       // [gridDim,10,10]
    int T)
{
    __shared__ __align__(16) float comp[1000];
    __shared__ __align__(16) float Pm[CH_WAVES][100];
    __shared__ __align__(16) float Em[CH_WAVES][100];
    __shared__ __align__(16) float Gm[CH_WAVES][CH_STEPS * 10];

    const int tid = threadIdx.x;
    const int w = tid >> 6, l = tid & 63;

    if (tid < 90) {
        const int g = tid / 9, i = tid % 9;
        const float* row = trans + (g * 9 + i) * 10;
        float v[10], m = -1e30f;
        #pragma unroll
        for (int j = 0; j < 10; ++j) { v[j] = row[j]; m = fmaxf(m, v[j]); }
        float e[10], sum = 0.f;
        #pragma unroll
        for (int j = 0; j < 10; ++j) { e[j] = __expf((v[j] - m) * 10.f); sum += e[j]; }
        const float inv = 1.f / sum;
        #pragma unroll
        for (int j = 0; j < 10; ++j) comp[g * 100 + i * 10 + j] = e[j] * inv;
    } else if (tid < 100) {
        const int g = tid - 90;
        #pragma unroll
        for (int j = 0; j < 10; ++j) comp[g * 100 + 90 + j] = (j == 9) ? 1.f : 0.f;
    }

    const int chunk = blockIdx.x * CH_WAVES + w;
    const int base  = chunk * CH_STEPS;
    const int nst   = min(CH_STEPS, T - base);

    if (l < 20 && base * 10 + l * 4 < T * 10) {
        const float4* gp = reinterpret_cast<const float4*>(guards + (size_t)base * 10);
        reinterpret_cast<float4*>(Gm[w])[l] = gp[l];
    }
    if (l < 50) {
        const int e0 = 2 * l, e1 = 2 * l + 1;
        Pm[w][e0] = (e0 / 10 == e0 % 10) ? 1.f : 0.f;
        Pm[w][e1] = (e1 / 10 == e1 % 10) ? 1.f : 0.f;
    }
    __syncthreads();

    const int e0 = 2 * l, i = e0 / 10, j = e0 % 10;
    if (l < 50) {
        for (int t = 0; t < nst; ++t) {
            float gv[10];
            #pragma unroll
            for (int g = 0; g < 10; ++g) gv[g] = Gm[w][t * 10 + g];
            float a = 0.f, b = 0.f;
            #pragma unroll
            for (int g = 0; g < 10; ++g) {
                const float2 c2 = *reinterpret_cast<const float2*>(&comp[g * 100 + e0]);
                a = fmaf(gv[g], c2.x, a);
                b = fmaf(gv[g], c2.y, b);
            }
            *reinterpret_cast<float2*>(&Em[w][e0]) = make_float2(a, b);
            __builtin_amdgcn_wave_barrier();
            asm volatile("s_waitcnt lgkmcnt(0)" ::: "memory");
            float s0 = 0.f, s1 = 0.f;
            #pragma unroll
            for (int k = 0; k < 10; ++k) {
                const float pk = Pm[w][i * 10 + k];
                const float2 ek = *reinterpret_cast<const float2*>(&Em[w][k * 10 + j]);
                s0 = fmaf(pk, ek.x, s0);
                s1 = fmaf(pk, ek.y, s1);
            }
            __builtin_amdgcn_wave_barrier();
            *reinterpret_cast<float2*>(&Pm[w][e0]) = make_float2(s0, s1);
            __builtin_amdgcn_wave_barrier();
        }
    }
    __syncthreads();

    if (w == 0 && l < 50) {
        float r0 = Pm[0][e0], r1 = Pm[0][e0 + 1];
        for (int q = 1; q < CH_WAVES; ++q) {
            *reinterpret_cast<float2*>(&Em[0][e0]) = make_float2(r0, r1);
            __builtin_amdgcn_wave_barrier();
            asm volatile("s_waitcnt lgkmcnt(0)" ::: "memory");
            float s0 = 0.f, s1 = 0.f;
            #pragma unroll
            for (int k = 0; k < 10; ++k) {
                const float rk = Em[0][i * 10 + k];
                const float2 pk2 = *reinterpret_cast<const float2*>(&Pm[q][k * 10 + j]);
                s0 = fmaf(rk, pk2.x, s0);
                s1 = fmaf(rk, pk2.y, s1);
            }
            r0 = s0; r1 = s1;
            __builtin_amdgcn_wave_barrier();
        }
        *reinterpret_cast<float2*>(&partials[(size_t)blockIdx.x * 100 + e0]) =
            make_float2(r0, r1);
    }
}

// ---------------------------------------------------------------------------
// Finalize (two-level): 8 waves each matrix-fold 16 partials in parallel,
// then wave 0 vector-folds the 8 wave results.
// ---------------------------------------------------------------------------
__global__ __launch_bounds__(512) void finalize_kernel(
    const float* __restrict__ partials, float* __restrict__ out_final, int nmat)
{
    __shared__ __align__(16) float sp[12800];      // 128 matrices, 51.2 KB
    __shared__ __align__(16) float Rt[8][100];
    __shared__ __align__(16) float Et[8][100];

    const int tid = threadIdx.x;
    const int w = tid >> 6, l = tid & 63;
    const int mpw = nmat / 8;                      // matrices per wave (16)

    for (int idx = tid; idx < nmat * 25; idx += 512)
        reinterpret_cast<float4*>(sp)[idx] = reinterpret_cast<const float4*>(partials)[idx];
    __syncthreads();

    const int e0 = 2 * l, i = e0 / 10, j = e0 % 10;
    if (l < 50) {
        const float* mybase = sp + (size_t)w * mpw * 100;
        float r0 = mybase[e0], r1 = mybase[e0 + 1];
        for (int q = 1; q < mpw; ++q) {
            *reinterpret_cast<float2*>(&Et[w][e0]) = make_float2(r0, r1);
            __builtin_amdgcn_wave_barrier();
            asm volatile("s_waitcnt lgkmcnt(0)" ::: "memory");
            float s0 = 0.f, s1 = 0.f;
            #pragma unroll
            for (int k = 0; k < 10; ++k) {
                const float rk = Et[w][i * 10 + k];
                const float2 pk2 = *reinterpret_cast<const float2*>(&mybase[q * 100 + k * 10 + j]);
                s0 = fmaf(rk, pk2.x, s0);
                s1 = fmaf(rk, pk2.y, s1);
            }
            r0 = s0; r1 = s1;
            __builtin_amdgcn_wave_barrier();
        }
        *reinterpret_cast<float2*>(&Rt[w][e0]) = make_float2(r0, r1);
    }
    __syncthreads();

    if (tid < 64) {                                // wave 0: vector fold of 8
        float s = (l == 0) ? 1.f : 0.f;
        for (int b = 0; b < 8; ++b) {
            float acc = 0.f;
            #pragma unroll
            for (int k = 0; k < 10; ++k) {
                const float pv = (l < 10) ? Rt[b][k * 10 + l] : 0.f;
                acc = fmaf(__shfl(s, k, 64), pv, acc);
            }
            s = acc;
        }
        if (l < 10) out_final[l] = s;
    }
}

extern "C" void kernel_launch(void* const* d_in, const int* in_sizes, int n_in,
                              void* d_out, int out_size, void* d_ws, size_t ws_size,
                              hipStream_t stream)
{
    const float* seq = (const float*)d_in[0];
    const float* w1  = (const float*)d_in[1];
    const float* b1  = (const float*)d_in[2];
    const float* w2  = (const float*)d_in[3];
    const float* b2  = (const float*)d_in[4];
    const float* w3  = (const float*)d_in[5];
    const float* b3  = (const float*)d_in[6];
    const float* wd  = (const float*)d_in[7];
    const float* bd  = (const float*)d_in[8];
    const float* tm  = (const float*)d_in[9];
    float* out = (float*)d_out;

    const int T = in_sizes[0] / 784;                       // 8192
    const int guard_off = T * 10;
    const int final_off = 2 * T * 10;
    const int nblk = (T + CH_WAVES * CH_STEPS - 1) / (CH_WAVES * CH_STEPS);  // 128

    float* partials = (float*)d_ws;                        // nblk*100 floats

    cnn_kernel<<<T / 2, 256, 0, stream>>>(seq, w1, b1, w2, b2, w3, b3, wd, bd,
                                          out, guard_off);
    chain_kernel<<<nblk, 512, 0, stream>>>(out, tm, partials, T);
    finalize_kernel<<<1, 512, 0, stream>>>(partials, out + final_off, nblk);
}